// Round 1
// baseline (6685.082 us; speedup 1.0000x reference)
//
#include <hip/hip_runtime.h>
#include <math.h>

// Problem constants (setup_inputs): B=32, Lq=Lk=D=1024
#define TM 64
#define TN 64
#define TK 16

// ---------------------------------------------------------------------------
// NT GEMM: C[M,N] = A[M,K] * B[N,K]^T  (both operands K-contiguous, row-major)
// MODE 0: plain store (q projection)
// MODE 1: masked scores store: C = mask ? acc : -1e9
// ---------------------------------------------------------------------------
template <int MODE>
__global__ __launch_bounds__(256) void gemm_nt_kernel(
    const float* __restrict__ A, const float* __restrict__ B,
    float* __restrict__ C, int M, int N, int K,
    long long aStride, long long bStride, long long cStride,
    const int* __restrict__ qlen, const int* __restrict__ klen)
{
    const int b = blockIdx.z;
    A += (size_t)b * aStride;
    B += (size_t)b * bStride;
    C += (size_t)b * cStride;

    __shared__ float As[TK][TM + 1];
    __shared__ float Bs[TK][TN + 1];

    const int tx = threadIdx.x, ty = threadIdx.y;
    const int tid = ty * 16 + tx;
    const int m0 = blockIdx.y * TM;
    const int n0 = blockIdx.x * TN;

    const int lr = tid >> 2;         // 0..63: tile row
    const int lc = (tid & 3) << 2;   // 0,4,8,12: k offset (float4)

    float acc[4][4];
#pragma unroll
    for (int i = 0; i < 4; i++)
#pragma unroll
        for (int j = 0; j < 4; j++) acc[i][j] = 0.f;

    for (int k0 = 0; k0 < K; k0 += TK) {
        float4 a4 = *(const float4*)(A + (size_t)(m0 + lr) * K + k0 + lc);
        float4 b4 = *(const float4*)(B + (size_t)(n0 + lr) * K + k0 + lc);
        As[lc + 0][lr] = a4.x; As[lc + 1][lr] = a4.y;
        As[lc + 2][lr] = a4.z; As[lc + 3][lr] = a4.w;
        Bs[lc + 0][lr] = b4.x; Bs[lc + 1][lr] = b4.y;
        Bs[lc + 2][lr] = b4.z; Bs[lc + 3][lr] = b4.w;
        __syncthreads();
#pragma unroll
        for (int k = 0; k < TK; k++) {
            float av[4], bv[4];
#pragma unroll
            for (int i = 0; i < 4; i++) av[i] = As[k][ty * 4 + i];
#pragma unroll
            for (int j = 0; j < 4; j++) bv[j] = Bs[k][tx * 4 + j];
#pragma unroll
            for (int i = 0; i < 4; i++)
#pragma unroll
                for (int j = 0; j < 4; j++)
                    acc[i][j] = fmaf(av[i], bv[j], acc[i][j]);
        }
        __syncthreads();
    }

    if (MODE == 0) {
#pragma unroll
        for (int i = 0; i < 4; i++) {
            int row = m0 + ty * 4 + i;
            float4 v = make_float4(acc[i][0], acc[i][1], acc[i][2], acc[i][3]);
            *(float4*)(C + (size_t)row * N + n0 + tx * 4) = v;
        }
    } else {
        const int qb = qlen[b];
        const int kb = klen[b];
#pragma unroll
        for (int i = 0; i < 4; i++) {
            int row = m0 + ty * 4 + i;
            bool rok = row < qb;
            float4 v;
            int c0 = n0 + tx * 4;
            v.x = (rok && (c0 + 0) < kb) ? acc[i][0] : -1e9f;
            v.y = (rok && (c0 + 1) < kb) ? acc[i][1] : -1e9f;
            v.z = (rok && (c0 + 2) < kb) ? acc[i][2] : -1e9f;
            v.w = (rok && (c0 + 3) < kb) ? acc[i][3] : -1e9f;
            *(float4*)(C + (size_t)row * N + c0) = v;
        }
    }
}

// ---------------------------------------------------------------------------
// Per-row softmax stats over scores: stats[row] = (rowmax, 1/sum(exp(x-max)))
// One wave per row; 4 rows per 256-thread block.
// ---------------------------------------------------------------------------
__global__ __launch_bounds__(256) void row_stats_kernel(
    const float* __restrict__ S, float2* __restrict__ stats, int L)
{
    const int row = blockIdx.x * 4 + (threadIdx.x >> 6);
    const int lane = threadIdx.x & 63;
    const float* p = S + (size_t)row * L;

    float mx = -1e30f;
    for (int j = lane; j < L; j += 64) mx = fmaxf(mx, p[j]);
#pragma unroll
    for (int off = 32; off > 0; off >>= 1) mx = fmaxf(mx, __shfl_xor(mx, off, 64));

    float sm = 0.f;
    for (int j = lane; j < L; j += 64) sm += expf(p[j] - mx);
#pragma unroll
    for (int off = 32; off > 0; off >>= 1) sm += __shfl_xor(sm, off, 64);

    if (lane == 0) stats[row] = make_float2(mx, 1.f / sm);
}

// ---------------------------------------------------------------------------
// NN GEMM with on-the-fly softmax on A:
// mix[b,i,d] = sum_k softmax(scores)[b,i,k] * ctx[b,k,d]
// A = scores [Lq,Lk] (K-contig), transformed exp(x-mx)*rinv while staging.
// B = ctx [Lk,D] row-major (N-contig).
// ---------------------------------------------------------------------------
__global__ __launch_bounds__(256) void gemm_mix_kernel(
    const float* __restrict__ S, const float2* __restrict__ stats,
    const float* __restrict__ ctx, float* __restrict__ mix,
    int Lq, int Lk, int D)
{
    const int b = blockIdx.z;
    S += (size_t)b * Lq * Lk;
    ctx += (size_t)b * Lk * D;
    mix += (size_t)b * Lq * D;
    stats += (size_t)b * Lq;

    __shared__ float As[TK][TM + 1];
    __shared__ float Bs[TK][TN + 1];

    const int tx = threadIdx.x, ty = threadIdx.y;
    const int tid = ty * 16 + tx;
    const int m0 = blockIdx.y * TM;
    const int n0 = blockIdx.x * TN;

    // A staging indices (K-contiguous)
    const int lr = tid >> 2;
    const int lc = (tid & 3) << 2;
    // B staging indices (N-contiguous)
    const int kr = tid >> 4;          // 0..15
    const int nc = (tid & 15) << 2;   // 0..60

    float acc[4][4];
#pragma unroll
    for (int i = 0; i < 4; i++)
#pragma unroll
        for (int j = 0; j < 4; j++) acc[i][j] = 0.f;

    const float2 st = stats[m0 + lr];   // stats for the A row this thread stages

    for (int k0 = 0; k0 < Lk; k0 += TK) {
        float4 a4 = *(const float4*)(S + (size_t)(m0 + lr) * Lk + k0 + lc);
        float4 b4 = *(const float4*)(ctx + (size_t)(k0 + kr) * D + n0 + nc);
        As[lc + 0][lr] = expf(a4.x - st.x) * st.y;
        As[lc + 1][lr] = expf(a4.y - st.x) * st.y;
        As[lc + 2][lr] = expf(a4.z - st.x) * st.y;
        As[lc + 3][lr] = expf(a4.w - st.x) * st.y;
        Bs[kr][nc + 0] = b4.x; Bs[kr][nc + 1] = b4.y;
        Bs[kr][nc + 2] = b4.z; Bs[kr][nc + 3] = b4.w;
        __syncthreads();
#pragma unroll
        for (int k = 0; k < TK; k++) {
            float av[4], bv[4];
#pragma unroll
            for (int i = 0; i < 4; i++) av[i] = As[k][ty * 4 + i];
#pragma unroll
            for (int j = 0; j < 4; j++) bv[j] = Bs[k][tx * 4 + j];
#pragma unroll
            for (int i = 0; i < 4; i++)
#pragma unroll
                for (int j = 0; j < 4; j++)
                    acc[i][j] = fmaf(av[i], bv[j], acc[i][j]);
        }
        __syncthreads();
    }

#pragma unroll
    for (int i = 0; i < 4; i++) {
        int row = m0 + ty * 4 + i;
        float4 v = make_float4(acc[i][0], acc[i][1], acc[i][2], acc[i][3]);
        *(float4*)(mix + (size_t)row * D + n0 + tx * 4) = v;
    }
}

// ---------------------------------------------------------------------------
// Output GEMM: out[m,d] = tanh( sum_{c<1024} mix[m,c]*W_out[d,c]
//                             + sum_{c<1024} q[m,c]*W_out[d,1024+c] )
// NT GEMM with K=2048, A split across two buffers (each K-stride 1024).
// ---------------------------------------------------------------------------
__global__ __launch_bounds__(256) void gemm_out_kernel(
    const float* __restrict__ A1, const float* __restrict__ A2,
    const float* __restrict__ B, float* __restrict__ C, int M, int N)
{
    const int Ka = 1024;   // per-buffer K
    const int K = 2048;    // total K (W_out row stride)

    __shared__ float As[TK][TM + 1];
    __shared__ float Bs[TK][TN + 1];

    const int tx = threadIdx.x, ty = threadIdx.y;
    const int tid = ty * 16 + tx;
    const int m0 = blockIdx.y * TM;
    const int n0 = blockIdx.x * TN;

    const int lr = tid >> 2;
    const int lc = (tid & 3) << 2;

    float acc[4][4];
#pragma unroll
    for (int i = 0; i < 4; i++)
#pragma unroll
        for (int j = 0; j < 4; j++) acc[i][j] = 0.f;

    for (int k0 = 0; k0 < K; k0 += TK) {
        const float* Asrc = (k0 < Ka) ? (A1 + k0) : (A2 + (k0 - Ka));
        float4 a4 = *(const float4*)(Asrc + (size_t)(m0 + lr) * Ka + lc);
        float4 b4 = *(const float4*)(B + (size_t)(n0 + lr) * K + k0 + lc);
        As[lc + 0][lr] = a4.x; As[lc + 1][lr] = a4.y;
        As[lc + 2][lr] = a4.z; As[lc + 3][lr] = a4.w;
        Bs[lc + 0][lr] = b4.x; Bs[lc + 1][lr] = b4.y;
        Bs[lc + 2][lr] = b4.z; Bs[lc + 3][lr] = b4.w;
        __syncthreads();
#pragma unroll
        for (int k = 0; k < TK; k++) {
            float av[4], bv[4];
#pragma unroll
            for (int i = 0; i < 4; i++) av[i] = As[k][ty * 4 + i];
#pragma unroll
            for (int j = 0; j < 4; j++) bv[j] = Bs[k][tx * 4 + j];
#pragma unroll
            for (int i = 0; i < 4; i++)
#pragma unroll
                for (int j = 0; j < 4; j++)
                    acc[i][j] = fmaf(av[i], bv[j], acc[i][j]);
        }
        __syncthreads();
    }

#pragma unroll
    for (int i = 0; i < 4; i++) {
        int row = m0 + ty * 4 + i;
        float4 v = make_float4(tanhf(acc[i][0]), tanhf(acc[i][1]),
                               tanhf(acc[i][2]), tanhf(acc[i][3]));
        *(float4*)(C + (size_t)row * N + n0 + tx * 4) = v;
    }
}

// ---------------------------------------------------------------------------
extern "C" void kernel_launch(void* const* d_in, const int* in_sizes, int n_in,
                              void* d_out, int out_size, void* d_ws, size_t ws_size,
                              hipStream_t stream)
{
    const float* query   = (const float*)d_in[0];   // [B,Lq,D]
    const float* context = (const float*)d_in[1];   // [B,Lk,D]
    const int*   qlens   = (const int*)d_in[2];     // [B]
    const int*   clens   = (const int*)d_in[3];     // [B]
    const float* W_in    = (const float*)d_in[4];   // [D,D]
    const float* W_out   = (const float*)d_in[5];   // [D,2D]

    const int B = 32, Lq = 1024, Lk = 1024, D = 1024;
    const size_t nQ = (size_t)B * Lq * D;   // 33,554,432

    float* out    = (float*)d_out;          // output [B,Lq,D]
    float* scores = out + nQ;               // scores_m [B,Lq,Lk]

    // workspace: q (128 MiB) | mix (128 MiB) | row stats (256 KiB)
    float*  q     = (float*)d_ws;
    float*  mix   = q + nQ;
    float2* stats = (float2*)(mix + nQ);

    dim3 blk(16, 16);

    // 1) q = query @ W_in^T   (one big [32768,1024]x[1024,1024]^T GEMM)
    gemm_nt_kernel<0><<<dim3(D / TN, (B * Lq) / TM, 1), blk, 0, stream>>>(
        query, W_in, q, B * Lq, D, D, 0LL, 0LL, 0LL, nullptr, nullptr);

    // 2) scores_m = mask(q @ ctx^T)  -> d_out (output 1)
    gemm_nt_kernel<1><<<dim3(Lk / TN, Lq / TM, B), blk, 0, stream>>>(
        q, context, scores, Lq, Lk, D,
        (long long)Lq * D, (long long)Lk * D, (long long)Lq * Lk, qlens, clens);

    // 3) per-row softmax stats
    row_stats_kernel<<<(B * Lq) / 4, 256, 0, stream>>>(scores, stats, Lk);

    // 4) mix = softmax(scores) @ ctx
    gemm_mix_kernel<<<dim3(D / TN, Lq / TM, B), blk, 0, stream>>>(
        scores, stats, context, mix, Lq, Lk, D);

    // 5) out = tanh([mix | q] @ W_out^T)
    gemm_out_kernel<<<dim3(D / TN, (B * Lq) / TM, 1), blk, 0, stream>>>(
        mix, q, W_out, out, B * Lq, D);
}

// Round 2
// 1882.194 us; speedup vs baseline: 3.5517x; 3.5517x over previous
//
#include <hip/hip_runtime.h>
#include <math.h>

// B=32, Lq=Lk=D=1024
#define BM 128
#define BN 128
#define BK 32
#define KP 40   // padded LDS K-stride in bf16 elems (80B rows, 16B-aligned frags)

typedef __bf16 bf16x8 __attribute__((ext_vector_type(8)));
typedef float  floatx4 __attribute__((ext_vector_type(4)));

__device__ __forceinline__ unsigned short f2bf(float x) {
    unsigned int u = __float_as_uint(x);
    u += 0x7FFFu + ((u >> 16) & 1u);           // RNE
    return (unsigned short)(u >> 16);
}
__device__ __forceinline__ float bf2f(unsigned short h) {
    return __uint_as_float(((unsigned int)h) << 16);
}

// convert float4 -> hi/lo bf16 quads, store 8B each into LDS
__device__ __forceinline__ void cvt_store(unsigned short* H, unsigned short* L,
                                          int idx, float4 v) {
    unsigned short h0 = f2bf(v.x), h1 = f2bf(v.y), h2 = f2bf(v.z), h3 = f2bf(v.w);
    *(ushort4*)(H + idx) = make_ushort4(h0, h1, h2, h3);
    unsigned short l0 = f2bf(v.x - bf2f(h0)), l1 = f2bf(v.y - bf2f(h1));
    unsigned short l2 = f2bf(v.z - bf2f(h2)), l3 = f2bf(v.w - bf2f(h3));
    *(ushort4*)(L + idx) = make_ushort4(l0, l1, l2, l3);
}

// ---------------------------------------------------------------------------
// Split-bf16 (3-pass) MFMA GEMM, NT: C[M,N] = A[M,K] * B[N,K]^T
// EPI: 0 = plain fp32 store, 1 = length-masked (-1e9) store, 2 = tanh store
// SOFTA:  A elements are softmax'd on the fly: a = exp(s - max)*rinv
// SPLITA: A is two concatenated K-halves (A for k<K/2, A2 for k>=K/2)
// TRANSB: B is [K][N] row-major in global (NN GEMM); staged fp32, frags
//         built via strided LDS reads + in-register hi/lo conversion
// ---------------------------------------------------------------------------
template <int EPI, bool SOFTA, bool SPLITA, bool TRANSB>
__global__ __launch_bounds__(256, 2) void mfma_gemm(
    const float* __restrict__ A, const float* __restrict__ A2,
    const float* __restrict__ B, float* __restrict__ C,
    int K, int lda, int ldb, int ldc,
    long long aBatch, long long bBatch, long long cBatch,
    const float2* __restrict__ stats, long long statsBatch,
    const int* __restrict__ qlen, const int* __restrict__ klen)
{
    const int b = blockIdx.z;
    A += aBatch * b;
    B += bBatch * b;
    C += cBatch * b;

    __shared__ __align__(16) unsigned short smem[(BM + BN) * KP * 2];
    unsigned short* Ah = smem;                // BM*KP
    unsigned short* Al = Ah + BM * KP;
    unsigned short* Bh = Al + BM * KP;        // BN*KP
    unsigned short* Bl = Bh + BN * KP;
    float* Bt = (float*)Bh;                   // TRANSB: 32 x 130 fp32 (16.6KB <= 20.5KB)

    const int tid = threadIdx.x;
    const int m0 = blockIdx.y * BM;
    const int n0 = blockIdx.x * BN;

    // staging indices (K-contig operands)
    const int sr = tid >> 3;                  // 0..31
    const int sc = (tid & 7) << 2;            // 0,4,...,28

    // wave / lane MFMA indices
    const int wv = tid >> 6;
    const int wm = (wv >> 1) << 6;            // 0 or 64
    const int wn = (wv & 1) << 6;
    const int lane = tid & 63;
    const int lm = lane & 15;
    const int lk = (lane >> 4) << 3;          // 0,8,16,24

    floatx4 acc[4][4];
#pragma unroll
    for (int i = 0; i < 4; i++)
#pragma unroll
        for (int j = 0; j < 4; j++) acc[i][j] = (floatx4)0.f;

    float2 st[4];
    if (SOFTA) {
        const float2* sp = stats + statsBatch * b;
#pragma unroll
        for (int r = 0; r < 4; r++) st[r] = sp[m0 + (r << 5) + sr];
    }

    for (int k0 = 0; k0 < K; k0 += BK) {
        // ---- stage A (fp32 -> hi/lo bf16) ----
        const float* Ap = A;
        int kk = k0;
        if (SPLITA) {
            const int half = K >> 1;
            Ap = (k0 < half) ? A : A2;
            kk = k0 & (half - 1);
        }
#pragma unroll
        for (int r = 0; r < 4; r++) {
            const int row = (r << 5) + sr;
            float4 v = *(const float4*)(Ap + (size_t)(m0 + row) * lda + kk + sc);
            if (SOFTA) {
                v.x = expf(v.x - st[r].x) * st[r].y;
                v.y = expf(v.y - st[r].x) * st[r].y;
                v.z = expf(v.z - st[r].x) * st[r].y;
                v.w = expf(v.w - st[r].x) * st[r].y;
            }
            cvt_store(Ah, Al, row * KP + sc, v);
        }
        // ---- stage B ----
        if (!TRANSB) {
#pragma unroll
            for (int r = 0; r < 4; r++) {
                const int row = (r << 5) + sr;
                float4 v = *(const float4*)(B + (size_t)(n0 + row) * ldb + k0 + sc);
                cvt_store(Bh, Bl, row * KP + sc, v);
            }
        } else {
            const int kr = tid >> 3;          // 0..31
            const int c4 = (tid & 7) << 2;
#pragma unroll
            for (int r = 0; r < 4; r++) {
                const int col = (r << 5) + c4;
                const float* src = B + (size_t)(k0 + kr) * ldb + n0 + col;
                float2 v0 = *(const float2*)(src);
                float2 v1 = *(const float2*)(src + 2);
                *(float2*)(Bt + kr * 130 + col) = v0;
                *(float2*)(Bt + kr * 130 + col + 2) = v1;
            }
        }
        __syncthreads();

        // ---- fragments ----
        bf16x8 ah[4], al[4], bh[4], bl[4];
#pragma unroll
        for (int t = 0; t < 4; t++) {
            const int ar = (wm + (t << 4) + lm) * KP + lk;
            ah[t] = *(const bf16x8*)(Ah + ar);
            al[t] = *(const bf16x8*)(Al + ar);
        }
        if (!TRANSB) {
#pragma unroll
            for (int t = 0; t < 4; t++) {
                const int br = (wn + (t << 4) + lm) * KP + lk;
                bh[t] = *(const bf16x8*)(Bh + br);
                bl[t] = *(const bf16x8*)(Bl + br);
            }
        } else {
#pragma unroll
            for (int t = 0; t < 4; t++) {
                const int n = wn + (t << 4) + lm;
                union { unsigned short u[8]; bf16x8 v; } th, tl;
#pragma unroll
                for (int j = 0; j < 8; j++) {
                    float x = Bt[(lk + j) * 130 + n];
                    unsigned short h = f2bf(x);
                    th.u[j] = h;
                    tl.u[j] = f2bf(x - bf2f(h));
                }
                bh[t] = th.v;
                bl[t] = tl.v;
            }
        }

        // ---- 3-pass MFMA ----
#pragma unroll
        for (int i = 0; i < 4; i++)
#pragma unroll
            for (int j = 0; j < 4; j++) {
                acc[i][j] = __builtin_amdgcn_mfma_f32_16x16x32_bf16(al[i], bh[j], acc[i][j], 0, 0, 0);
                acc[i][j] = __builtin_amdgcn_mfma_f32_16x16x32_bf16(ah[i], bl[j], acc[i][j], 0, 0, 0);
                acc[i][j] = __builtin_amdgcn_mfma_f32_16x16x32_bf16(ah[i], bh[j], acc[i][j], 0, 0, 0);
            }
        __syncthreads();
    }

    // ---- epilogue ----
    int qb = 0, kb = 0;
    if (EPI == 1) { qb = qlen[b]; kb = klen[b]; }
    const int qd = (lane >> 4) << 2;
#pragma unroll
    for (int i = 0; i < 4; i++)
#pragma unroll
        for (int j = 0; j < 4; j++) {
            const int col = n0 + wn + (j << 4) + lm;
#pragma unroll
            for (int r = 0; r < 4; r++) {
                const int row = m0 + wm + (i << 4) + qd + r;
                float v = acc[i][j][r];
                if (EPI == 1) v = (row < qb && col < kb) ? v : -1e9f;
                else if (EPI == 2) v = tanhf(v);
                C[(size_t)row * ldc + col] = v;
            }
        }
}

// ---------------------------------------------------------------------------
// Per-row softmax stats: stats[row] = (rowmax, 1/sum(exp(x-max)))
// ---------------------------------------------------------------------------
__global__ __launch_bounds__(256) void row_stats_kernel(
    const float* __restrict__ S, float2* __restrict__ stats, int L)
{
    const int row = blockIdx.x * 4 + (threadIdx.x >> 6);
    const int lane = threadIdx.x & 63;
    const float* p = S + (size_t)row * L;

    float mx = -1e30f;
    for (int j = lane; j < L; j += 64) mx = fmaxf(mx, p[j]);
#pragma unroll
    for (int off = 32; off > 0; off >>= 1) mx = fmaxf(mx, __shfl_xor(mx, off, 64));

    float sm = 0.f;
    for (int j = lane; j < L; j += 64) sm += expf(p[j] - mx);
#pragma unroll
    for (int off = 32; off > 0; off >>= 1) sm += __shfl_xor(sm, off, 64);

    if (lane == 0) stats[row] = make_float2(mx, 1.f / sm);
}

// ---------------------------------------------------------------------------
extern "C" void kernel_launch(void* const* d_in, const int* in_sizes, int n_in,
                              void* d_out, int out_size, void* d_ws, size_t ws_size,
                              hipStream_t stream)
{
    const float* query   = (const float*)d_in[0];   // [B,Lq,D]
    const float* context = (const float*)d_in[1];   // [B,Lk,D]
    const int*   qlens   = (const int*)d_in[2];     // [B]
    const int*   clens   = (const int*)d_in[3];     // [B]
    const float* W_in    = (const float*)d_in[4];   // [D,D]
    const float* W_out   = (const float*)d_in[5];   // [D,2D]

    const int B = 32, Lq = 1024, Lk = 1024, D = 1024;
    const long long nQ = (long long)B * Lq * D;     // 33,554,432

    float* out    = (float*)d_out;                  // [B,Lq,D]
    float* scores = out + nQ;                       // [B,Lq,Lk]

    float*  q     = (float*)d_ws;                   // 128 MiB
    float*  mix   = q + nQ;                         // 128 MiB
    float2* stats = (float2*)(mix + nQ);            // 256 KiB

    // 1) q = query @ W_in^T   [32768,1024] x [1024,1024]^T
    mfma_gemm<0, false, false, false><<<dim3(D / BN, (B * Lq) / BM, 1), 256, 0, stream>>>(
        query, nullptr, W_in, q, D, D, D, D,
        0LL, 0LL, 0LL, nullptr, 0LL, nullptr, nullptr);

    // 2) scores_m = mask(q @ ctx^T)  (batched NT)
    mfma_gemm<1, false, false, false><<<dim3(Lk / BN, Lq / BM, B), 256, 0, stream>>>(
        q, nullptr, context, scores, D, D, D, Lk,
        (long long)Lq * D, (long long)Lk * D, (long long)Lq * Lk,
        nullptr, 0LL, qlens, clens);

    // 3) per-row softmax stats
    row_stats_kernel<<<(B * Lq) / 4, 256, 0, stream>>>(scores, stats, Lk);

    // 4) mix = softmax(scores) @ ctx   (batched NN: TRANSB, softmax on the fly)
    mfma_gemm<0, true, false, true><<<dim3(D / BN, Lq / BM, B), 256, 0, stream>>>(
        scores, nullptr, context, mix, Lk, Lk, D, D,
        (long long)Lq * Lk, (long long)Lk * D, (long long)Lq * D,
        stats, (long long)Lq, nullptr, nullptr);

    // 5) out = tanh([mix | q] @ W_out^T)   (K=2048 split-A NT)
    mfma_gemm<2, false, true, false><<<dim3(D / BN, (B * Lq) / BM, 1), 256, 0, stream>>>(
        mix, q, W_out, out, 2 * D, D, 2 * D, D,
        0LL, 0LL, 0LL, nullptr, 0LL, nullptr, nullptr);
}